// Round 10
// baseline (91.720 us; speedup 1.0000x reference)
//
#include <hip/hip_runtime.h>
#include <math.h>

// grid layout: 1600 blocks x 256 threads, each block owns a contiguous 512-row chunk.
// prog 512 blocks (heads 0,1) | stck 256 (2,3,4) | locl 256 (5,6)
// heap 512 (7,8) | call 64 (9)
// ws: 3392 x u64 per-(block,head) packed winners (grouped per head),
//     then u32 completion counter (zeroed per call by a memset node).
#define NBLOCKS 1600
#define CTR_OFF 3392

__device__ __constant__ int HOFF[10] = {0, 512, 1024, 1280, 1536, 1792, 2048, 2304, 2816, 3328};
__device__ __constant__ int HCNT[10] = {512, 512, 256, 256, 256, 256, 256, 512, 512, 64};

static __device__ __forceinline__ unsigned int fkey(float f) {
  unsigned int u = __float_as_uint(f);
  return (u & 0x80000000u) ? ~u : (u | 0x80000000u);
}
static __device__ __forceinline__ float funkey(unsigned int k) {
  unsigned int u = (k & 0x80000000u) ? (k & 0x7fffffffu) : ~k;
  return __uint_as_float(u);
}
static __device__ __forceinline__ float dot4(float4 a, float4 b) {
  return a.x * b.x + a.y * b.y + a.z * b.z + a.w * b.w;
}

// ---- single fused kernel: prep + scan + block-winner store + last-block epilogue.
__global__ __launch_bounds__(256) void fused_kernel(
    const float* __restrict__ query,
    const float* __restrict__ prog, const float* __restrict__ stck,
    const float* __restrict__ locl, const float* __restrict__ heap,
    const float* __restrict__ call,
    const float* __restrict__ WQ, const float* __restrict__ bQ,
    const float* __restrict__ WK,
    const float* __restrict__ WV1, const float* __restrict__ WVc,
    float* __restrict__ ws, float* __restrict__ out)
{
  unsigned long long* res = (unsigned long long*)ws;
  unsigned int* ctr = (unsigned int*)(res + CTR_OFF);
  int b = blockIdx.x, tid = threadIdx.x;

  const float* mem; int h0, nh, brank, off0, off1, off2;
  if (b < 512)       { mem = prog; h0 = 0; nh = 2; brank = b;        off0 = 0    + brank; off1 = 512  + brank; off2 = 0; }
  else if (b < 768)  { mem = stck; h0 = 2; nh = 3; brank = b - 512;  off0 = 1024 + brank; off1 = 1280 + brank; off2 = 1536 + brank; }
  else if (b < 1024) { mem = locl; h0 = 5; nh = 2; brank = b - 768;  off0 = 1792 + brank; off1 = 2048 + brank; off2 = 0; }
  else if (b < 1536) { mem = heap; h0 = 7; nh = 2; brank = b - 1024; off0 = 2304 + brank; off1 = 2816 + brank; off2 = 0; }
  else               { mem = call; h0 = 9; nh = 1; brank = b - 1536; off0 = 3328 + brank; off1 = 0;            off2 = 0; }

  // ---- phase 0: q (serial 64-dot, bitwise-identical to reference) + k_eff in LDS
  __shared__ float qs[6];
  __shared__ float skeff[3][64];
  if (tid < 2 * nh) {
    const float* wq = WQ + (h0 * 2 + tid) * 64;
    float s = bQ[h0 * 2 + tid];
    for (int d = 0; d < 64; ++d) s += wq[d] * query[d];
    qs[tid] = s;
  }
  __syncthreads();
  if (tid < 192) {
    int hi = tid >> 6, d = tid & 63;
    float v = 0.f;
    if (hi < nh) {
      int h = h0 + hi;
      v = qs[2 * hi] * WK[(h * 2) * 64 + d] + qs[2 * hi + 1] * WK[(h * 2 + 1) * 64 + d];
    }
    skeff[hi][d] = v;
  }
  __syncthreads();

  // ---- phase 1: scan 512 rows, 8 iters x 64 rows; 4 lanes/row (R5 layout).
  int lane4 = tid & 3, rsub = tid >> 2;

  float4 ka[4], kb[4], kc[4];
#pragma unroll
  for (int j = 0; j < 4; ++j) {
    ka[j] = ((const float4*)skeff[0])[j * 4 + lane4];
    kb[j] = ((const float4*)skeff[1])[j * 4 + lane4];
    kc[j] = ((const float4*)skeff[2])[j * 4 + lane4];
  }

  float bsA = -INFINITY, bsB = -INFINITY, bsC = -INFINITY;
  int biA = 0, biB = 0, biC = 0;
  int base = brank * 512;
#pragma unroll 2
  for (int it = 0; it < 8; ++it) {
    int r = base + it * 64 + rsub;
    const float* rowp = mem + (size_t)r * 64 + lane4 * 4;
    float4 v0 = *(const float4*)(rowp +  0);
    float4 v1 = *(const float4*)(rowp + 16);
    float4 v2 = *(const float4*)(rowp + 32);
    float4 v3 = *(const float4*)(rowp + 48);

    float sA = dot4(v0, ka[0]) + dot4(v1, ka[1]) + dot4(v2, ka[2]) + dot4(v3, ka[3]);
    float sB = dot4(v0, kb[0]) + dot4(v1, kb[1]) + dot4(v2, kb[2]) + dot4(v3, kb[3]);
    float sC = dot4(v0, kc[0]) + dot4(v1, kc[1]) + dot4(v2, kc[2]) + dot4(v3, kc[3]);

    sA += __shfl_xor(sA, 1); sA += __shfl_xor(sA, 2);
    sB += __shfl_xor(sB, 1); sB += __shfl_xor(sB, 2);
    sC += __shfl_xor(sC, 1); sC += __shfl_xor(sC, 2);

    if (sA > bsA) { bsA = sA; biA = r; }
    if (sB > bsB) { bsB = sB; biB = r; }
    if (sC > bsC) { bsC = sC; biC = r; }
  }

  // ---- phase 2: block reduce, non-atomic store of packed (key, ~idx)
  unsigned long long p0 = ((unsigned long long)fkey(bsA) << 32) | (unsigned long long)(0xFFFFFFFFu - (unsigned)biA);
  unsigned long long p1 = ((unsigned long long)fkey(bsB) << 32) | (unsigned long long)(0xFFFFFFFFu - (unsigned)biB);
  unsigned long long p2 = ((unsigned long long)fkey(bsC) << 32) | (unsigned long long)(0xFFFFFFFFu - (unsigned)biC);
#pragma unroll
  for (int m = 4; m < 64; m <<= 1) {   // lanes within 4-group already identical
    unsigned long long t;
    t = __shfl_xor(p0, m); if (t > p0) p0 = t;
    t = __shfl_xor(p1, m); if (t > p1) p1 = t;
    t = __shfl_xor(p2, m); if (t > p2) p2 = t;
  }
  __shared__ unsigned long long red[3][4];
  __shared__ int slast;
  int wv = tid >> 6;
  if ((tid & 63) == 0) { red[0][wv] = p0; red[1][wv] = p1; red[2][wv] = p2; }
  __syncthreads();
  if (tid == 0) {
    unsigned long long m0 = red[0][0], m1 = red[1][0], m2 = red[2][0];
#pragma unroll
    for (int w = 1; w < 4; ++w) {
      if (red[0][w] > m0) m0 = red[0][w];
      if (red[1][w] > m1) m1 = red[1][w];
      if (red[2][w] > m2) m2 = red[2][w];
    }
    res[off0] = m0;
    if (nh > 1) res[off1] = m1;
    if (nh > 2) res[off2] = m2;
    __threadfence();                              // release winners
    unsigned int prev = atomicAdd(ctr, 1u);
    slast = (prev == NBLOCKS - 1) ? 1 : 0;
  }
  __syncthreads();
  if (slast == 0) return;

  // ---- phase 3 (last block only): per-head max over winners, then value dots
  __threadfence();                                // acquire winners
  __shared__ int sidx[10];
  int w = tid >> 6, lane = tid & 63;              // 4 waves
  for (int h = w; h < 10; h += 4) {
    const unsigned long long* basep = res + HOFF[h];
    int n = HCNT[h];
    unsigned long long m = 0ull;
    for (int i = lane; i < n; i += 64) {
      unsigned long long v = basep[i];
      if (v > m) m = v;
    }
#pragma unroll
    for (int s = 1; s < 64; s <<= 1) {
      unsigned long long t = __shfl_xor(m, s);
      if (t > m) m = t;
    }
    if (lane == 0) {
      unsigned int key = (unsigned int)(m >> 32);
      int idx = (int)(0xFFFFFFFFu - (unsigned int)(m & 0xFFFFFFFFull));
      sidx[h] = idx;
      out[12 + h] = funkey(key);      // best_scores
      out[22 + h] = (float)idx;       // best_idx (as f32)
    }
  }
  __syncthreads();
  int p = tid >> 4, l = tid & 15;
  if (p < 12) {
    int hh = (p < 9) ? p : 9;
    const float* wrow = (p < 9) ? (WV1 + p * 64) : (WVc + (p - 9) * 64);
    const float* vmem;
    if (hh < 2) vmem = prog;
    else if (hh < 5) vmem = stck;
    else if (hh < 7) vmem = locl;
    else if (hh < 9) vmem = heap;
    else vmem = call;
    const float* row = vmem + (size_t)sidx[hh] * 64;
    float s = 0.f;
#pragma unroll
    for (int j = 0; j < 4; ++j) s += wrow[l * 4 + j] * row[l * 4 + j];
#pragma unroll
    for (int m2 = 1; m2 < 16; m2 <<= 1) s += __shfl_xor(s, m2);
    if (l == 0) out[p] = s;
  }
}

extern "C" void kernel_launch(void* const* d_in, const int* in_sizes, int n_in,
                              void* d_out, int out_size, void* d_ws, size_t ws_size,
                              hipStream_t stream) {
  const float* query = (const float*)d_in[0];
  const float* prog  = (const float*)d_in[1];
  const float* stck  = (const float*)d_in[2];
  const float* locl  = (const float*)d_in[3];
  const float* heap  = (const float*)d_in[4];
  const float* call  = (const float*)d_in[5];
  const float* WQ    = (const float*)d_in[6];
  const float* bQ    = (const float*)d_in[7];
  const float* WK    = (const float*)d_in[8];
  const float* WV1   = (const float*)d_in[9];
  const float* WVc   = (const float*)d_in[10];
  float* ws  = (float*)d_ws;
  float* out = (float*)d_out;

  // zero the completion counter (d_ws is poisoned 0xAA once, never re-poisoned)
  hipMemsetAsync((char*)d_ws + CTR_OFF * sizeof(unsigned long long), 0,
                 sizeof(unsigned int), stream);

  hipLaunchKernelGGL(fused_kernel, dim3(NBLOCKS), dim3(256), 0, stream,
                     query, prog, stck, locl, heap, call, WQ, bQ, WK,
                     WV1, WVc, ws, out);
}

// Round 11
// 63.437 us; speedup vs baseline: 1.4459x; 1.4459x over previous
//
#include <hip/hip_runtime.h>
#include <math.h>

// grid layout: 1600 blocks x 256 threads, each block owns a contiguous 512-row chunk.
// prog 512 blocks (heads 0,1) | stck 256 (2,3,4) | locl 256 (5,6)
// heap 512 (7,8) | call 64 (9)
// ws: 3392 x u64 per-(block,head) packed winners (grouped per head),
//     then u32 completion counter (zeroed per call by a memset node).
// Cross-XCD visibility WITHOUT __threadfence (R10 lesson: per-block device
// fences trigger chip-wide L2 writebacks -> 2x slowdown). Winners are stored
// with agent-scope atomic stores (write-through, line-granular), completion
// is ordered by s_waitcnt vmcnt(0), and the last block reads winners with
// agent-scope atomic loads (stale-cache bypass).
#define NBLOCKS 1600
#define CTR_OFF 3392

__device__ __constant__ int HOFF[10] = {0, 512, 1024, 1280, 1536, 1792, 2048, 2304, 2816, 3328};
__device__ __constant__ int HCNT[10] = {512, 512, 256, 256, 256, 256, 256, 512, 512, 64};

static __device__ __forceinline__ unsigned int fkey(float f) {
  unsigned int u = __float_as_uint(f);
  return (u & 0x80000000u) ? ~u : (u | 0x80000000u);
}
static __device__ __forceinline__ float funkey(unsigned int k) {
  unsigned int u = (k & 0x80000000u) ? (k & 0x7fffffffu) : ~k;
  return __uint_as_float(u);
}
static __device__ __forceinline__ float dot4(float4 a, float4 b) {
  return a.x * b.x + a.y * b.y + a.z * b.z + a.w * b.w;
}

// ---- single fused kernel: prep + scan + winner store + last-block epilogue.
__global__ __launch_bounds__(256) void fused_kernel(
    const float* __restrict__ query,
    const float* __restrict__ prog, const float* __restrict__ stck,
    const float* __restrict__ locl, const float* __restrict__ heap,
    const float* __restrict__ call,
    const float* __restrict__ WQ, const float* __restrict__ bQ,
    const float* __restrict__ WK,
    const float* __restrict__ WV1, const float* __restrict__ WVc,
    float* __restrict__ ws, float* __restrict__ out)
{
  unsigned long long* res = (unsigned long long*)ws;
  unsigned int* ctr = (unsigned int*)(res + CTR_OFF);
  int b = blockIdx.x, tid = threadIdx.x;

  const float* mem; int h0, nh, brank, off0, off1, off2;
  if (b < 512)       { mem = prog; h0 = 0; nh = 2; brank = b;        off0 = 0    + brank; off1 = 512  + brank; off2 = 0; }
  else if (b < 768)  { mem = stck; h0 = 2; nh = 3; brank = b - 512;  off0 = 1024 + brank; off1 = 1280 + brank; off2 = 1536 + brank; }
  else if (b < 1024) { mem = locl; h0 = 5; nh = 2; brank = b - 768;  off0 = 1792 + brank; off1 = 2048 + brank; off2 = 0; }
  else if (b < 1536) { mem = heap; h0 = 7; nh = 2; brank = b - 1024; off0 = 2304 + brank; off1 = 2816 + brank; off2 = 0; }
  else               { mem = call; h0 = 9; nh = 1; brank = b - 1536; off0 = 3328 + brank; off1 = 0;            off2 = 0; }

  // ---- phase 0: q (serial 64-dot, bitwise-identical to reference) + k_eff in LDS
  __shared__ float qs[6];
  __shared__ float skeff[3][64];
  if (tid < 2 * nh) {
    const float* wq = WQ + (h0 * 2 + tid) * 64;
    float s = bQ[h0 * 2 + tid];
    for (int d = 0; d < 64; ++d) s += wq[d] * query[d];
    qs[tid] = s;
  }
  __syncthreads();
  if (tid < 192) {
    int hi = tid >> 6, d = tid & 63;
    float v = 0.f;
    if (hi < nh) {
      int h = h0 + hi;
      v = qs[2 * hi] * WK[(h * 2) * 64 + d] + qs[2 * hi + 1] * WK[(h * 2 + 1) * 64 + d];
    }
    skeff[hi][d] = v;
  }
  __syncthreads();

  // ---- phase 1: scan 512 rows, 8 iters x 64 rows; 4 lanes/row (R5 layout).
  int lane4 = tid & 3, rsub = tid >> 2;

  float4 ka[4], kb[4], kc[4];
#pragma unroll
  for (int j = 0; j < 4; ++j) {
    ka[j] = ((const float4*)skeff[0])[j * 4 + lane4];
    kb[j] = ((const float4*)skeff[1])[j * 4 + lane4];
    kc[j] = ((const float4*)skeff[2])[j * 4 + lane4];
  }

  float bsA = -INFINITY, bsB = -INFINITY, bsC = -INFINITY;
  int biA = 0, biB = 0, biC = 0;
  int base = brank * 512;
#pragma unroll 2
  for (int it = 0; it < 8; ++it) {
    int r = base + it * 64 + rsub;
    const float* rowp = mem + (size_t)r * 64 + lane4 * 4;
    float4 v0 = *(const float4*)(rowp +  0);
    float4 v1 = *(const float4*)(rowp + 16);
    float4 v2 = *(const float4*)(rowp + 32);
    float4 v3 = *(const float4*)(rowp + 48);

    float sA = dot4(v0, ka[0]) + dot4(v1, ka[1]) + dot4(v2, ka[2]) + dot4(v3, ka[3]);
    float sB = dot4(v0, kb[0]) + dot4(v1, kb[1]) + dot4(v2, kb[2]) + dot4(v3, kb[3]);
    float sC = dot4(v0, kc[0]) + dot4(v1, kc[1]) + dot4(v2, kc[2]) + dot4(v3, kc[3]);

    sA += __shfl_xor(sA, 1); sA += __shfl_xor(sA, 2);
    sB += __shfl_xor(sB, 1); sB += __shfl_xor(sB, 2);
    sC += __shfl_xor(sC, 1); sC += __shfl_xor(sC, 2);

    if (sA > bsA) { bsA = sA; biA = r; }
    if (sB > bsB) { bsB = sB; biB = r; }
    if (sC > bsC) { bsC = sC; biC = r; }
  }

  // ---- phase 2: block reduce; winner store via agent-scope atomic stores
  unsigned long long p0 = ((unsigned long long)fkey(bsA) << 32) | (unsigned long long)(0xFFFFFFFFu - (unsigned)biA);
  unsigned long long p1 = ((unsigned long long)fkey(bsB) << 32) | (unsigned long long)(0xFFFFFFFFu - (unsigned)biB);
  unsigned long long p2 = ((unsigned long long)fkey(bsC) << 32) | (unsigned long long)(0xFFFFFFFFu - (unsigned)biC);
#pragma unroll
  for (int m = 4; m < 64; m <<= 1) {   // lanes within 4-group already identical
    unsigned long long t;
    t = __shfl_xor(p0, m); if (t > p0) p0 = t;
    t = __shfl_xor(p1, m); if (t > p1) p1 = t;
    t = __shfl_xor(p2, m); if (t > p2) p2 = t;
  }
  __shared__ unsigned long long red[3][4];
  __shared__ int slast;
  int wv = tid >> 6;
  if ((tid & 63) == 0) { red[0][wv] = p0; red[1][wv] = p1; red[2][wv] = p2; }
  __syncthreads();
  if (tid == 0) {
    unsigned long long m0 = red[0][0], m1 = red[1][0], m2 = red[2][0];
#pragma unroll
    for (int w = 1; w < 4; ++w) {
      if (red[0][w] > m0) m0 = red[0][w];
      if (red[1][w] > m1) m1 = red[1][w];
      if (red[2][w] > m2) m2 = red[2][w];
    }
    __hip_atomic_store(&res[off0], m0, __ATOMIC_RELAXED, __HIP_MEMORY_SCOPE_AGENT);
    if (nh > 1) __hip_atomic_store(&res[off1], m1, __ATOMIC_RELAXED, __HIP_MEMORY_SCOPE_AGENT);
    if (nh > 2) __hip_atomic_store(&res[off2], m2, __ATOMIC_RELAXED, __HIP_MEMORY_SCOPE_AGENT);
    // order: winner stores must have REACHED the coherence point before the
    // counter bump. Hardware-completion ordering, no cache fence.
    asm volatile("s_waitcnt vmcnt(0)" ::: "memory");
    unsigned int prev = __hip_atomic_fetch_add(ctr, 1u, __ATOMIC_RELAXED, __HIP_MEMORY_SCOPE_AGENT);
    slast = (prev == NBLOCKS - 1) ? 1 : 0;
  }
  __syncthreads();
  if (slast == 0) return;

  // ---- phase 3 (last block only): per-head max over winners, then value dots
  __shared__ int sidx[10];
  int w = tid >> 6, lane = tid & 63;              // 4 waves
  for (int h = w; h < 10; h += 4) {
    const unsigned long long* basep = res + HOFF[h];
    int n = HCNT[h];
    unsigned long long m = 0ull;
    for (int i = lane; i < n; i += 64) {
      unsigned long long v = __hip_atomic_load(&basep[i], __ATOMIC_RELAXED, __HIP_MEMORY_SCOPE_AGENT);
      if (v > m) m = v;
    }
#pragma unroll
    for (int s = 1; s < 64; s <<= 1) {
      unsigned long long t = __shfl_xor(m, s);
      if (t > m) m = t;
    }
    if (lane == 0) {
      unsigned int key = (unsigned int)(m >> 32);
      int idx = (int)(0xFFFFFFFFu - (unsigned int)(m & 0xFFFFFFFFull));
      sidx[h] = idx;
      out[12 + h] = funkey(key);      // best_scores
      out[22 + h] = (float)idx;       // best_idx (as f32)
    }
  }
  __syncthreads();
  int p = tid >> 4, l = tid & 15;
  if (p < 12) {
    int hh = (p < 9) ? p : 9;
    const float* wrow = (p < 9) ? (WV1 + p * 64) : (WVc + (p - 9) * 64);
    const float* vmem;
    if (hh < 2) vmem = prog;
    else if (hh < 5) vmem = stck;
    else if (hh < 7) vmem = locl;
    else if (hh < 9) vmem = heap;
    else vmem = call;
    const float* row = vmem + (size_t)sidx[hh] * 64;
    float s = 0.f;
#pragma unroll
    for (int j = 0; j < 4; ++j) s += wrow[l * 4 + j] * row[l * 4 + j];
#pragma unroll
    for (int m2 = 1; m2 < 16; m2 <<= 1) s += __shfl_xor(s, m2);
    if (l == 0) out[p] = s;
  }
}

extern "C" void kernel_launch(void* const* d_in, const int* in_sizes, int n_in,
                              void* d_out, int out_size, void* d_ws, size_t ws_size,
                              hipStream_t stream) {
  const float* query = (const float*)d_in[0];
  const float* prog  = (const float*)d_in[1];
  const float* stck  = (const float*)d_in[2];
  const float* locl  = (const float*)d_in[3];
  const float* heap  = (const float*)d_in[4];
  const float* call  = (const float*)d_in[5];
  const float* WQ    = (const float*)d_in[6];
  const float* bQ    = (const float*)d_in[7];
  const float* WK    = (const float*)d_in[8];
  const float* WV1   = (const float*)d_in[9];
  const float* WVc   = (const float*)d_in[10];
  float* ws  = (float*)d_ws;
  float* out = (float*)d_out;

  // zero the completion counter (d_ws is poisoned 0xAA once, never re-poisoned)
  hipMemsetAsync((char*)d_ws + CTR_OFF * sizeof(unsigned long long), 0,
                 sizeof(unsigned int), stream);

  hipLaunchKernelGGL(fused_kernel, dim3(NBLOCKS), dim3(256), 0, stream,
                     query, prog, stck, locl, heap, call, WQ, bQ, WK,
                     WV1, WVc, ws, out);
}

// Round 12
// 47.058 us; speedup vs baseline: 1.9491x; 1.3480x over previous
//
#include <hip/hip_runtime.h>
#include <math.h>

// grid layout: 1600 blocks, each owns a contiguous 512-row chunk.
// prog 512 blocks (heads 0,1) | stck 256 (2,3,4) | locl 256 (5,6)
// heap 512 (7,8) | call 64 (9)
// ws: 3392 x u64 per-(block,head) packed winners, grouped per head.
__device__ __constant__ int HOFF[10] = {0, 512, 1024, 1280, 1536, 1792, 2048, 2304, 2816, 3328};
__device__ __constant__ int HCNT[10] = {512, 512, 256, 256, 256, 256, 256, 512, 512, 64};

static __device__ __forceinline__ unsigned int fkey(float f) {
  unsigned int u = __float_as_uint(f);
  return (u & 0x80000000u) ? ~u : (u | 0x80000000u);
}
static __device__ __forceinline__ float funkey(unsigned int k) {
  unsigned int u = (k & 0x80000000u) ? (k & 0x7fffffffu) : ~k;
  return __uint_as_float(u);
}
static __device__ __forceinline__ float dot4(float4 a, float4 b) {
  return a.x * b.x + a.y * b.y + a.z * b.z + a.w * b.w;
}

// ---- kernel 1: per-block prep (q + k_eff in LDS) + scan + block-winner store.
__global__ __launch_bounds__(256) void scan_kernel(
    const float* __restrict__ query,
    const float* __restrict__ prog, const float* __restrict__ stck,
    const float* __restrict__ locl, const float* __restrict__ heap,
    const float* __restrict__ call,
    const float* __restrict__ WQ, const float* __restrict__ bQ,
    const float* __restrict__ WK, float* __restrict__ ws)
{
  unsigned long long* res = (unsigned long long*)ws;
  int b = blockIdx.x, tid = threadIdx.x;

  const float* mem; int h0, nh, brank, off0, off1, off2;
  if (b < 512)       { mem = prog; h0 = 0; nh = 2; brank = b;        off0 = 0    + brank; off1 = 512  + brank; off2 = 0; }
  else if (b < 768)  { mem = stck; h0 = 2; nh = 3; brank = b - 512;  off0 = 1024 + brank; off1 = 1280 + brank; off2 = 1536 + brank; }
  else if (b < 1024) { mem = locl; h0 = 5; nh = 2; brank = b - 768;  off0 = 1792 + brank; off1 = 2048 + brank; off2 = 0; }
  else if (b < 1536) { mem = heap; h0 = 7; nh = 2; brank = b - 1024; off0 = 2304 + brank; off1 = 2816 + brank; off2 = 0; }
  else               { mem = call; h0 = 9; nh = 1; brank = b - 1536; off0 = 3328 + brank; off1 = 0;            off2 = 0; }

  // ---- phase 0: q (serial 64-dot, bitwise-identical to reference) + k_eff in LDS
  __shared__ float qs[6];
  __shared__ float skeff[3][64];
  if (tid < 2 * nh) {
    const float* wq = WQ + (h0 * 2 + tid) * 64;
    float s = bQ[h0 * 2 + tid];
    for (int d = 0; d < 64; ++d) s += wq[d] * query[d];
    qs[tid] = s;
  }
  __syncthreads();
  if (tid < 192) {
    int hi = tid >> 6, d = tid & 63;
    float v = 0.f;
    if (hi < nh) {
      int h = h0 + hi;
      v = qs[2 * hi] * WK[(h * 2) * 64 + d] + qs[2 * hi + 1] * WK[(h * 2 + 1) * 64 + d];
    }
    skeff[hi][d] = v;
  }
  __syncthreads();

  // ---- phase 1: scan 512 rows. 4 lanes per row; each load instruction covers
  // 16 FULL 64B cache lines (lanes 0-3 contiguous within a line).
  int lane4 = tid & 3, rsub = tid >> 2;

  float4 ka[4], kb[4], kc[4];
#pragma unroll
  for (int j = 0; j < 4; ++j) {
    ka[j] = ((const float4*)skeff[0])[j * 4 + lane4];
    kb[j] = ((const float4*)skeff[1])[j * 4 + lane4];
    kc[j] = ((const float4*)skeff[2])[j * 4 + lane4];
  }

  float bsA = -INFINITY, bsB = -INFINITY, bsC = -INFINITY;
  int biA = 0, biB = 0, biC = 0;
  int base = brank * 512;
#pragma unroll 2
  for (int it = 0; it < 8; ++it) {
    int r = base + it * 64 + rsub;
    const float* rowp = mem + (size_t)r * 64 + lane4 * 4;
    float4 v0 = *(const float4*)(rowp +  0);  // floats lane4*4 +  0.. 3
    float4 v1 = *(const float4*)(rowp + 16);  // floats lane4*4 + 16..19
    float4 v2 = *(const float4*)(rowp + 32);
    float4 v3 = *(const float4*)(rowp + 48);

    float sA = dot4(v0, ka[0]) + dot4(v1, ka[1]) + dot4(v2, ka[2]) + dot4(v3, ka[3]);
    float sB = dot4(v0, kb[0]) + dot4(v1, kb[1]) + dot4(v2, kb[2]) + dot4(v3, kb[3]);
    float sC = dot4(v0, kc[0]) + dot4(v1, kc[1]) + dot4(v2, kc[2]) + dot4(v3, kc[3]);

    sA += __shfl_xor(sA, 1); sA += __shfl_xor(sA, 2);
    sB += __shfl_xor(sB, 1); sB += __shfl_xor(sB, 2);
    sC += __shfl_xor(sC, 1); sC += __shfl_xor(sC, 2);

    if (sA > bsA) { bsA = sA; biA = r; }
    if (sB > bsB) { bsB = sB; biB = r; }
    if (sC > bsC) { bsC = sC; biC = r; }
  }

  // ---- phase 2: block reduce, non-atomic store of packed (key, ~idx)
  unsigned long long p0 = ((unsigned long long)fkey(bsA) << 32) | (unsigned long long)(0xFFFFFFFFu - (unsigned)biA);
  unsigned long long p1 = ((unsigned long long)fkey(bsB) << 32) | (unsigned long long)(0xFFFFFFFFu - (unsigned)biB);
  unsigned long long p2 = ((unsigned long long)fkey(bsC) << 32) | (unsigned long long)(0xFFFFFFFFu - (unsigned)biC);
#pragma unroll
  for (int m = 4; m < 64; m <<= 1) {   // lanes within 4-group already identical
    unsigned long long t;
    t = __shfl_xor(p0, m); if (t > p0) p0 = t;
    t = __shfl_xor(p1, m); if (t > p1) p1 = t;
    t = __shfl_xor(p2, m); if (t > p2) p2 = t;
  }
  __shared__ unsigned long long red[3][4];
  int wv = tid >> 6;
  if ((tid & 63) == 0) { red[0][wv] = p0; red[1][wv] = p1; red[2][wv] = p2; }
  __syncthreads();
  if (tid == 0) {
    unsigned long long m0 = red[0][0], m1 = red[1][0], m2 = red[2][0];
#pragma unroll
    for (int w = 1; w < 4; ++w) {
      if (red[0][w] > m0) m0 = red[0][w];
      if (red[1][w] > m1) m1 = red[1][w];
      if (red[2][w] > m2) m2 = red[2][w];
    }
    res[off0] = m0;
    if (nh > 1) res[off1] = m1;
    if (nh > 2) res[off2] = m2;
  }
}

// ---- kernel 2: reduce per-head winner arrays (1 wave per head), then 12 value dots.
__global__ __launch_bounds__(640) void epi_kernel(
    const float* __restrict__ prog, const float* __restrict__ stck,
    const float* __restrict__ locl, const float* __restrict__ heap,
    const float* __restrict__ call,
    const float* __restrict__ WV1, const float* __restrict__ WVc,
    const float* __restrict__ ws, float* __restrict__ out) {
  const unsigned long long* res = (const unsigned long long*)ws;
  __shared__ int sidx[10];
  int tid = threadIdx.x;
  int w = tid >> 6, lane = tid & 63;
  if (w < 10) {
    const unsigned long long* basep = res + HOFF[w];
    int n = HCNT[w];
    unsigned long long m = 0ull;
    for (int i = lane; i < n; i += 64) {
      unsigned long long v = basep[i];
      if (v > m) m = v;
    }
#pragma unroll
    for (int s = 1; s < 64; s <<= 1) {
      unsigned long long t = __shfl_xor(m, s);
      if (t > m) m = t;
    }
    if (lane == 0) {
      unsigned int key = (unsigned int)(m >> 32);
      int idx = (int)(0xFFFFFFFFu - (unsigned int)(m & 0xFFFFFFFFull));
      sidx[w] = idx;
      out[12 + w] = funkey(key);      // best_scores
      out[22 + w] = (float)idx;       // best_idx (as f32)
    }
  }
  __syncthreads();
  int p = tid >> 4, l = tid & 15;
  if (p < 12) {
    int hh = (p < 9) ? p : 9;
    const float* wrow = (p < 9) ? (WV1 + p * 64) : (WVc + (p - 9) * 64);
    const float* vmem;
    if (hh < 2) vmem = prog;
    else if (hh < 5) vmem = stck;
    else if (hh < 7) vmem = locl;
    else if (hh < 9) vmem = heap;
    else vmem = call;
    const float* row = vmem + (size_t)sidx[hh] * 64;
    float s = 0.f;
#pragma unroll
    for (int j = 0; j < 4; ++j) s += wrow[l * 4 + j] * row[l * 4 + j];
#pragma unroll
    for (int m2 = 1; m2 < 16; m2 <<= 1) s += __shfl_xor(s, m2);
    if (l == 0) out[p] = s;
  }
}

extern "C" void kernel_launch(void* const* d_in, const int* in_sizes, int n_in,
                              void* d_out, int out_size, void* d_ws, size_t ws_size,
                              hipStream_t stream) {
  const float* query = (const float*)d_in[0];
  const float* prog  = (const float*)d_in[1];
  const float* stck  = (const float*)d_in[2];
  const float* locl  = (const float*)d_in[3];
  const float* heap  = (const float*)d_in[4];
  const float* call  = (const float*)d_in[5];
  const float* WQ    = (const float*)d_in[6];
  const float* bQ    = (const float*)d_in[7];
  const float* WK    = (const float*)d_in[8];
  const float* WV1   = (const float*)d_in[9];
  const float* WVc   = (const float*)d_in[10];
  float* ws  = (float*)d_ws;
  float* out = (float*)d_out;

  hipLaunchKernelGGL(scan_kernel, dim3(1600), dim3(256), 0, stream,
                     query, prog, stck, locl, heap, call, WQ, bQ, WK, ws);
  hipLaunchKernelGGL(epi_kernel, dim3(1), dim3(640), 0, stream,
                     prog, stck, locl, heap, call, WV1, WVc, ws, out);
}